// Round 1
// baseline (223.870 us; speedup 1.0000x reference)
//
#include <hip/hip_runtime.h>

#define HH 256
#define WW 704
#define DD 64
#define CC 3
#define BB 2
#define HWN (HH * WW)   // 180224, divisible by 256

static constexpr float INV2Z2 = 1.0f / (2.0f * 1e-3f * 1e-3f);  // 1/(2*zeta^2) = 5e5

// ---------------------------------------------------------------------------
// Affinity kernel: kaff[b,k,n] = ws * exp(-sum_c (uc[c,k,n]-color[c,n])^2 / (2 zeta^2))
// Zero padding: out-of-bounds neighbor value is 0, so diff = -center (contributes center^2).
// ---------------------------------------------------------------------------
__global__ __launch_bounds__(256) void affinity_kernel(
    const float* __restrict__ color, const float* __restrict__ wsp,
    float* __restrict__ kaff)
{
    int n = blockIdx.x * 256 + threadIdx.x;
    int b = blockIdx.y;
    int h = n / WW, w = n - h * WW;
    float wsv = wsp[0];

    const float* cb = color + (size_t)b * CC * HWN + n;
    float c0 = cb[0], c1 = cb[HWN], c2 = cb[2 * HWN];
    bool hm = h > 0, hp = h < HH - 1, wm = w > 0, wp = w < WW - 1;

    float* kb = kaff + (size_t)b * 9 * HWN + n;
#pragma unroll
    for (int dh = -1; dh <= 1; ++dh) {
#pragma unroll
        for (int dw = -1; dw <= 1; ++dw) {
            int k = (dh + 1) * 3 + (dw + 1);
            bool valid = (dh < 0 ? hm : (dh > 0 ? hp : true)) &&
                         (dw < 0 ? wm : (dw > 0 ? wp : true));
            int off = valid ? (dh * WW + dw) : 0;
            float u0 = valid ? cb[off] : 0.f;
            float u1 = valid ? cb[HWN + off] : 0.f;
            float u2 = valid ? cb[2 * HWN + off] : 0.f;
            float d0 = u0 - c0, d1 = u1 - c1, d2 = u2 - c2;
            float ss = d0 * d0 + d1 * d1 + d2 * d2;
            kb[(size_t)k * HWN] = wsv * __expf(-ss * INV2Z2);
        }
    }
}

// ---------------------------------------------------------------------------
// Initial softmax over D (axis=1), layout [B,D,HW], coalesced along n.
// ---------------------------------------------------------------------------
__global__ __launch_bounds__(256) void softmax0_kernel(
    const float* __restrict__ logits, float* __restrict__ q)
{
    int n = blockIdx.x * 256 + threadIdx.x;
    int b = blockIdx.y;
    const float* lg = logits + (size_t)b * DD * HWN + n;

    float m = -3.0e38f;
#pragma unroll 8
    for (int d = 0; d < DD; ++d) m = fmaxf(m, lg[(size_t)d * HWN]);
    float s = 0.f;
#pragma unroll 8
    for (int d = 0; d < DD; ++d) s += __expf(lg[(size_t)d * HWN] - m);
    float inv = 1.0f / s;
    float* qb = q + (size_t)b * DD * HWN + n;
#pragma unroll 8
    for (int d = 0; d < DD; ++d) qb[(size_t)d * HWN] = __expf(lg[(size_t)d * HWN] - m) * inv;
}

// ---------------------------------------------------------------------------
// One CRF iteration:
//   t[e]     = sum_k kaff[k,n] * q[e, nbr_k(n)]           (ws folded into kaff)
//   q_hat[d] = sum_e |d-e| t[e]  via prefix sums:
//              A[d]=sum_{e<=d} t, Bp[d]=sum_{e<=d} e*t, T=A[63], E=Bp[63]
//              q_hat[d] = 2(d*A[d]-Bp[d]) + E - d*T  =: c[d] + E - d*T
//   q_out    = softmax_d(logits - q_hat)
// One thread per pixel; c[64] in registers (loops fully unrolled, rule #20).
// Border: clamp offsets to in-bounds and zero the corresponding weights.
// ---------------------------------------------------------------------------
__global__ __launch_bounds__(256) void crf_iter_kernel(
    const float* __restrict__ qin, const float* __restrict__ logits,
    const float* __restrict__ kaff, float* __restrict__ qout)
{
    int n = blockIdx.x * 256 + threadIdx.x;
    int b = blockIdx.y;
    int h = n / WW, w = n - h * WW;

    const float* kb = kaff + (size_t)b * 9 * HWN + n;
    float k0 = kb[0];
    float k1 = kb[1 * HWN];
    float k2 = kb[2 * HWN];
    float k3 = kb[3 * HWN];
    float k4 = kb[4 * HWN];
    float k5 = kb[5 * HWN];
    float k6 = kb[6 * HWN];
    float k7 = kb[7 * HWN];
    float k8 = kb[8 * HWN];

    bool hm = h > 0, hp = h < HH - 1, wm = w > 0, wp = w < WW - 1;
    if (!hm) { k0 = k1 = k2 = 0.f; }
    if (!hp) { k6 = k7 = k8 = 0.f; }
    if (!wm) { k0 = k3 = k6 = 0.f; }
    if (!wp) { k2 = k5 = k8 = 0.f; }
    int oN = hm ? -WW : 0, oS = hp ? WW : 0;
    int oW = wm ? -1 : 0,  oE = wp ? 1 : 0;

    const float* qp = qin + (size_t)b * DD * HWN + n;

    float c[DD];
    float A = 0.f, Bp = 0.f;
#pragma unroll
    for (int e = 0; e < DD; ++e) {
        const float* qe = qp + (size_t)e * HWN;
        float t = k0 * qe[oN + oW] + k1 * qe[oN] + k2 * qe[oN + oE]
                + k3 * qe[oW]      + k4 * qe[0]  + k5 * qe[oE]
                + k6 * qe[oS + oW] + k7 * qe[oS] + k8 * qe[oS + oE];
        A += t;
        Bp += (float)e * t;
        c[e] = 2.0f * ((float)e * A - Bp);
    }
    float T = A, E = Bp;

    const float* lg = logits + (size_t)b * DD * HWN + n;

    // online softmax over d (branchless)
    float m = -3.0e38f, s = 0.f;
#pragma unroll
    for (int d = 0; d < DD; ++d) {
        float v = lg[(size_t)d * HWN] - (c[d] + E - (float)d * T);
        float mn = fmaxf(m, v);
        s = s * __expf(m - mn) + __expf(v - mn);
        m = mn;
    }
    float inv = 1.0f / s;

    float* qo = qout + (size_t)b * DD * HWN + n;
#pragma unroll
    for (int d = 0; d < DD; ++d) {
        float v = lg[(size_t)d * HWN] - (c[d] + E - (float)d * T);
        qo[(size_t)d * HWN] = __expf(v - m) * inv;
    }
}

// ---------------------------------------------------------------------------
extern "C" void kernel_launch(void* const* d_in, const int* in_sizes, int n_in,
                              void* d_out, int out_size, void* d_ws, size_t ws_size,
                              hipStream_t stream) {
    const float* color  = (const float*)d_in[0];
    // d_in[1] = feats: unused by the forward pass
    const float* logits = (const float*)d_in[2];
    const float* wsp    = (const float*)d_in[3];

    float* q_out = (float*)d_out;                       // q0, then final q
    float* kaff  = (float*)d_ws;                        // [B,9,HW]  ~13 MB
    float* q1    = (float*)d_ws + (size_t)BB * 9 * HWN; // [B,D,HW]  ~92 MB

    dim3 grid(HWN / 256, BB);
    affinity_kernel<<<grid, 256, 0, stream>>>(color, wsp, kaff);
    softmax0_kernel<<<grid, 256, 0, stream>>>(logits, q_out);
    crf_iter_kernel<<<grid, 256, 0, stream>>>(q_out, logits, kaff, q1);
    crf_iter_kernel<<<grid, 256, 0, stream>>>(q1, logits, kaff, q_out);
}